// Round 6
// baseline (580.739 us; speedup 1.0000x reference)
//
#include <hip/hip_runtime.h>

typedef unsigned short u16;
typedef unsigned short ushort8 __attribute__((ext_vector_type(8)));
typedef unsigned short us4 __attribute__((ext_vector_type(4)));
typedef __bf16 bf16x8 __attribute__((ext_vector_type(8)));
typedef float f32x4 __attribute__((ext_vector_type(4)));

#define DEV static __device__ __forceinline__

// ---------- helpers ----------
DEV u16 f2bf(float f) {   // round-to-nearest-even f32 -> bf16
    unsigned int u = __builtin_bit_cast(unsigned int, f);
    u += 0x7FFFu + ((u >> 16) & 1u);
    return (u16)(u >> 16);
}

DEV f32x4 mfma16(ushort8 a, ushort8 b, f32x4 c) {
    return __builtin_amdgcn_mfma_f32_16x16x32_bf16((bf16x8)a, (bf16x8)b, c, 0, 0, 0);
}

DEV void gload_lds16(const void* g, void* l) {   // async global->LDS, dst = base + lane*16
    __builtin_amdgcn_global_load_lds(
        (const __attribute__((address_space(1))) void*)g,
        (__attribute__((address_space(3))) void*)l, 16, 0, 0);
}

// ---------- fp32 -> bf16 elementwise ----------
__global__ void cvt_kernel(const float* __restrict__ in, u16* __restrict__ out, int n) {
    int i = (blockIdx.x * 256 + threadIdx.x) * 4;
    if (i >= n) return;
    float4 f = *(const float4*)(in + i);
    us4 o;
    o.x = f2bf(f.x); o.y = f2bf(f.y); o.z = f2bf(f.z); o.w = f2bf(f.w);
    *(us4*)(out + i) = o;
}

// ---------- fp32 [R][C] -> bf16 [C][R] (tiled, coalesced both sides) ----------
__global__ void transpose_cvt(const float* __restrict__ in, u16* __restrict__ out, int R, int C) {
    __shared__ u16 tile[64][72];
    int c0 = blockIdx.x << 6, r0 = blockIdx.y << 6;
    int tx = threadIdx.x & 63, ty = threadIdx.x >> 6;
    for (int i = 0; i < 64; i += 4) {
        int r = i + ty;
        tile[r][tx] = f2bf(in[(size_t)(r0 + r) * C + c0 + tx]);
    }
    __syncthreads();
    for (int i = 0; i < 64; i += 4) {
        int r = i + ty;
        out[(size_t)(c0 + r) * R + r0 + tx] = tile[tx][r];
    }
}

// ---------- bf16 [bh][2048][512] -> bf16 [bh][512][2048] ----------
__global__ void transpose_bh(const u16* __restrict__ in, u16* __restrict__ out) {
    __shared__ u16 tile[64][72];
    int bh = blockIdx.z;
    int d0 = blockIdx.x << 6, t0 = blockIdx.y << 6;
    int tx = threadIdx.x & 63, ty = threadIdx.x >> 6;
    const u16* src = in + (size_t)bh * 2048 * 512;
    u16* dst = out + (size_t)bh * 512 * 2048;
    for (int i = 0; i < 64; i += 4) {
        int r = i + ty;
        tile[r][tx] = src[(size_t)(t0 + r) * 512 + d0 + tx];
    }
    __syncthreads();
    for (int i = 0; i < 64; i += 4) {
        int r = i + ty;
        dst[(size_t)(d0 + r) * 2048 + t0 + tx] = tile[tx][r];
    }
}

// ---------- GEMM: C[M][?] = A[M][Kc](bf16) @ Bt[N][Kc]^T(bf16) ----------
template <int MODE>
__launch_bounds__(256, 2)
__global__ void gemm_bt(const u16* __restrict__ A, const u16* __restrict__ Bt,
                        float scale, const float* __restrict__ bias,
                        void* __restrict__ out, int Kc) {
    __shared__ u16 Asub[128 * 32];
    __shared__ u16 Bsub[128 * 32];
    const int tid = threadIdx.x, lane = tid & 63, wv = tid >> 6;
    const int bm = blockIdx.y << 7, bn = blockIdx.x << 7;
    const int wr = (wv >> 1) << 6, wc = (wv & 1) << 6;
    const int lr = lane & 15, hi = lane >> 4;

    f32x4 acc[4][4] = {};

    int off0 = (wv * 2048 + lane * 16) >> 1;
    int row0 = off0 >> 5, k0e = off0 & 31;
    int off1 = off0 + 512;
    int row1 = off1 >> 5, k1e = off1 & 31;

    const u16* Ag0 = A + (size_t)(bm + row0) * Kc + k0e;
    const u16* Ag1 = A + (size_t)(bm + row1) * Kc + k1e;
    const u16* Bg0 = Bt + (size_t)(bn + row0) * Kc + k0e;
    const u16* Bg1 = Bt + (size_t)(bn + row1) * Kc + k1e;

    for (int kk = 0; kk < Kc; kk += 32) {
        __syncthreads();
        gload_lds16(Ag0 + kk, &Asub[wv * 1024]);
        gload_lds16(Ag1 + kk, &Asub[wv * 1024 + 512]);
        gload_lds16(Bg0 + kk, &Bsub[wv * 1024]);
        gload_lds16(Bg1 + kk, &Bsub[wv * 1024 + 512]);
        __syncthreads();

        ushort8 a[4], b[4];
#pragma unroll
        for (int m = 0; m < 4; ++m)
            a[m] = *(const ushort8*)&Asub[(wr + m * 16 + lr) * 32 + hi * 8];
#pragma unroll
        for (int n = 0; n < 4; ++n)
            b[n] = *(const ushort8*)&Bsub[(wc + n * 16 + lr) * 32 + hi * 8];
#pragma unroll
        for (int m = 0; m < 4; ++m)
#pragma unroll
            for (int n = 0; n < 4; ++n)
                acc[m][n] = mfma16(a[m], b[n], acc[m][n]);
    }

#pragma unroll
    for (int m = 0; m < 4; ++m)
#pragma unroll
        for (int n = 0; n < 4; ++n)
#pragma unroll
            for (int r = 0; r < 4; ++r) {
                int row = bm + wr + m * 16 + hi * 4 + r;
                int col = bn + wc + n * 16 + lr;
                float v = acc[m][n][r] * scale;
                if constexpr (MODE == 0) {
                    size_t dst = ((size_t)((row >> 11) * 8 + (col >> 9)) * 2048 + (row & 2047)) * 512
                                 + (col & 511);
                    ((u16*)out)[dst] = f2bf(v);
                } else {
                    ((float*)out)[(size_t)row * 512 + col] = v + bias[col];
                }
            }
}

// ---------- flash attention v6 ----------
// v6 = v5 with the T3/T4 counted-vmcnt schedule (occupancy is register-bound at
// 2 waves/SIMD: acc 128 AGPR + 128 VGPR = 256 regs/lane; so we shorten the
// exposed critical path instead of adding waves).
//  * K triple-buffered (3 x 32KB), prefetch issued 2 tiles ahead.
//  * __syncthreads() replaced by lgkmcnt(0) + COUNTED vmcnt + raw s_barrier:
//    K(t+2) DMA and V(t) loads stay in flight across the barrier; only K(t+1)
//    (issued a full iteration earlier) is awaited. No vmcnt(0) drain in the loop.
//  * V(t) loads issued at iteration TOP (before the K prefetch in issue order,
//    so compiler vf-use waits never force the K DMA; vmcnt retires in-order).
// Protocol audit: K(t) awaited at barrier(t-1) [vmcnt(12): newest 12 = V(t)8+K(t+2)4
// may remain; tail iters vmcnt(8)]; P dbuf write/read distance 2 spans barrier(t+1);
// K buffer reuse distance 3 spans a barrier + per-wave wait.
__launch_bounds__(512, 2)
__global__ void attn_kernel(const u16* __restrict__ Q, const u16* __restrict__ K,
                            const u16* __restrict__ Vt, u16* __restrict__ O) {
    __shared__ u16 Klds[3][32 * 512];            // 3 x 32KB, XOR-swizzled rows
    __shared__ u16 Plds[2][128 * 40];            // [q][32 keys + 8 pad]
    __shared__ __align__(16) float red[2][128];  // per-row alpha
    __shared__ __align__(16) float lred[128];    // final l
    __shared__ int rflag[2][8];                  // per-wave "some row rescaled"

    const int tid = threadIdx.x, lane = tid & 63, wv = tid >> 6;
    const int lr = lane & 15, hi = lane >> 4;
    const int qh = wv >> 2, ds = wv & 3;         // PV decomposition

    // XCD-chunked bijective swizzle: 256 blocks = 8 XCDs x 32; 2 bh per XCD chunk
    const int flat = blockIdx.x;
    const int nid = (flat & 7) * 32 + (flat >> 3);
    const int bh = nid >> 4;
    const int q0 = (nid & 15) << 7;

    // Q fragments (B-operand: col=lane&15 -> q-row wv*16+lr, k-slice hi*8..+8)
    ushort8 qf[16];
    {
        const char* Qg = (const char*)(Q + ((size_t)bh * 2048 + q0 + wv * 16 + lr) * 512) + hi * 16;
#pragma unroll
        for (int ks = 0; ks < 16; ++ks) qf[ks] = *(const ushort8*)(Qg + ks * 64);
    }

    f32x4 acc[4][8] = {};   // [q 16-block within 64-row half][d 16-frag within 128-wide slice]
    float mrun = -1e30f, lrun = 0.f;   // per-lane, q = wv*16+lr (replicated over hi), base-2

    const char* Kg = (const char*)(K + (size_t)bh * 2048 * 512);
    const char* Vg = (const char*)(Vt + (size_t)bh * 512 * 2048);

    // prologue: stage K(0)->buf0, K(1)->buf1 (wave wv stages rows [wv*4, wv*4+4))
#pragma unroll
    for (int tt = 0; tt < 2; ++tt) {
        const char* Kgt = Kg + (size_t)tt * 32 * 1024;
#pragma unroll
        for (int r4 = 0; r4 < 4; ++r4) {
            int r = wv * 4 + r4;
            gload_lds16(Kgt + (size_t)r * 1024 + ((lane ^ (r & 7)) << 4),
                        &Klds[tt][(size_t)r * 512]);
        }
    }
    asm volatile("s_waitcnt vmcnt(4)" ::: "memory");   // K(0) landed; K(1) in flight
    __builtin_amdgcn_sched_barrier(0);
    __builtin_amdgcn_s_barrier();

    int kb = 0;   // buffer holding K(t)
    for (int t = 0; t < 64; ++t) {
        const int kt = t << 5;
        const int cb = t & 1;

        // V(t) loads FIRST (oldest VMEM of this iter: their use-waits never drain K DMA)
        ushort8 vf[8];
#pragma unroll
        for (int nf = 0; nf < 8; ++nf) {
            int d = ds * 128 + nf * 16 + lr;
            vf[nf] = *(const ushort8*)(Vg + (size_t)d * 4096 + (size_t)kt * 2 + hi * 16);
        }

        // prefetch K(t+2) into buffer (kb+2)%3
        if (t + 2 < 64) {
            const int kb2 = (kb >= 1) ? kb - 1 : 2;   // (kb+2)%3
            const char* Kgt = Kg + (size_t)(kt + 64) * 1024;
#pragma unroll
            for (int r4 = 0; r4 < 4; ++r4) {
                int r = wv * 4 + r4;
                gload_lds16(Kgt + (size_t)r * 1024 + ((lane ^ (r & 7)) << 4),
                            &Klds[kb2][(size_t)r * 512]);
            }
        }

        // S^T = K Q^T on Klds[kb] (awaited at previous barrier). 4 chains for ILP.
        f32x4 s0a = {}, s0b = {}, s1a = {}, s1b = {};
        const char* Kb = (const char*)&Klds[kb][0];
        __builtin_amdgcn_s_setprio(1);
#pragma unroll
        for (int ks = 0; ks < 8; ++ks) {
            int swz0 = (ks * 64 + hi * 16) ^ ((lr & 7) << 4);
            int swz1 = ((ks + 8) * 64 + hi * 16) ^ ((lr & 7) << 4);
            ushort8 kf0a = *(const ushort8*)(Kb + lr * 1024 + swz0);
            ushort8 kf1a = *(const ushort8*)(Kb + (lr + 16) * 1024 + swz0);
            ushort8 kf0b = *(const ushort8*)(Kb + lr * 1024 + swz1);
            ushort8 kf1b = *(const ushort8*)(Kb + (lr + 16) * 1024 + swz1);
            s0a = mfma16(kf0a, qf[ks], s0a);
            s1a = mfma16(kf1a, qf[ks], s1a);
            s0b = mfma16(kf0b, qf[ks + 8], s0b);
            s1b = mfma16(kf1b, qf[ks + 8], s1b);
        }
        __builtin_amdgcn_s_setprio(0);
        f32x4 s0, s1;
#pragma unroll
        for (int r = 0; r < 4; ++r) { s0[r] = s0a[r] + s0b[r]; s1[r] = s1a[r] + s1b[r]; }

        // lane-local online softmax (base-2) for q = wv*16+lr
        float mx = fmaxf(fmaxf(fmaxf(s0[0], s0[1]), fmaxf(s0[2], s0[3])),
                         fmaxf(fmaxf(s1[0], s1[1]), fmaxf(s1[2], s1[3])));
        mx = fmaxf(mx, __shfl_xor(mx, 16));
        mx = fmaxf(mx, __shfl_xor(mx, 32));
        float a = 1.0f;
        bool upd = false;
        if (mx > mrun + 11.5f) { a = exp2f(mrun - mx); mrun = mx; upd = true; }   // defer-max
        float p[8];
#pragma unroll
        for (int r = 0; r < 4; ++r) {
            p[r]     = exp2f(s0[r] - mrun);
            p[4 + r] = exp2f(s1[r] - mrun);
        }
        float ps = ((p[0] + p[1]) + (p[2] + p[3])) + ((p[4] + p[5]) + (p[6] + p[7]));
        ps += __shfl_xor(ps, 16);
        ps += __shfl_xor(ps, 32);
        lrun = lrun * a + ps;

        // P -> LDS (bf16 pairs), alpha, flag
        {
            const int qr = wv * 16 + lr;
            char* Pb = (char*)&Plds[cb][0] + qr * 80;
            uint2 w01, w23;
            w01.x = (unsigned)f2bf(p[0]) | ((unsigned)f2bf(p[1]) << 16);
            w01.y = (unsigned)f2bf(p[2]) | ((unsigned)f2bf(p[3]) << 16);
            w23.x = (unsigned)f2bf(p[4]) | ((unsigned)f2bf(p[5]) << 16);
            w23.y = (unsigned)f2bf(p[6]) | ((unsigned)f2bf(p[7]) << 16);
            *(uint2*)(Pb + hi * 8) = w01;
            *(uint2*)(Pb + 32 + hi * 8) = w23;
            if (hi == 0) red[cb][qr] = a;
        }
        if (lane == 0) rflag[cb][wv] = __any(upd) ? 1 : 0;

        // counted-wait barrier: P visible (lgkm); K(t+1) landed (vmcnt); K(t+2)+V(t) stay in flight
        asm volatile("s_waitcnt lgkmcnt(0)" ::: "memory");
        if (t < 62) { asm volatile("s_waitcnt vmcnt(12)" ::: "memory"); }
        else        { asm volatile("s_waitcnt vmcnt(8)"  ::: "memory"); }
        __builtin_amdgcn_sched_barrier(0);
        __builtin_amdgcn_s_barrier();
        __builtin_amdgcn_sched_barrier(0);

        // rescale O only if some row's max moved (defer-max)
        int anyupd = rflag[cb][0] | rflag[cb][1] | rflag[cb][2] | rflag[cb][3]
                   | rflag[cb][4] | rflag[cb][5] | rflag[cb][6] | rflag[cb][7];
        if (anyupd) {
#pragma unroll
            for (int mf = 0; mf < 4; ++mf) {
                f32x4 a4 = *(const f32x4*)&red[cb][qh * 64 + mf * 16 + hi * 4];
#pragma unroll
                for (int nf = 0; nf < 8; ++nf)
#pragma unroll
                    for (int r = 0; r < 4; ++r) acc[mf][nf][r] *= a4[r];
            }
        }

        // PV: pf from LDS, vf already in regs (loaded at top, landed during S+softmax)
        ushort8 pf[4];
#pragma unroll
        for (int mf = 0; mf < 4; ++mf)
            pf[mf] = *(const ushort8*)((const char*)&Plds[cb][0]
                                       + (qh * 64 + mf * 16 + lr) * 80 + hi * 16);
        __builtin_amdgcn_s_setprio(1);
#pragma unroll
        for (int nf = 0; nf < 8; ++nf)
#pragma unroll
            for (int mf = 0; mf < 4; ++mf) acc[mf][nf] = mfma16(pf[mf], vf[nf], acc[mf][nf]);
        __builtin_amdgcn_s_setprio(0);

        kb = (kb == 2) ? 0 : kb + 1;
    }

    // final l for all 128 rows -> LDS
    if (hi == 0) lred[wv * 16 + lr] = lrun;
    __syncthreads();

    const int b = bh >> 3, h = bh & 7;
#pragma unroll
    for (int mf = 0; mf < 4; ++mf) {
        f32x4 lv = *(const f32x4*)&lred[qh * 64 + mf * 16 + hi * 4];
        f32x4 inv;
#pragma unroll
        for (int r = 0; r < 4; ++r) inv[r] = 1.0f / lv[r];
#pragma unroll
        for (int nf = 0; nf < 8; ++nf) {
            int d = ds * 128 + nf * 16 + lr;
#pragma unroll
            for (int r = 0; r < 4; ++r) {
                int t = q0 + qh * 64 + mf * 16 + hi * 4 + r;
                O[((size_t)(b * 2048 + t)) * 4096 + h * 512 + d] = f2bf(acc[mf][nf][r] * inv[r]);
            }
        }
    }
}

// ---------- host ----------
extern "C" void kernel_launch(void* const* d_in, const int* in_sizes, int n_in,
                              void* d_out, int out_size, void* d_ws, size_t ws_size,
                              hipStream_t stream) {
    const float* x  = (const float*)d_in[0];
    const float* Wq = (const float*)d_in[1];
    const float* Wk = (const float*)d_in[2];
    const float* Wv = (const float*)d_in[3];
    const float* Wu = (const float*)d_in[4];
    const float* bu = (const float*)d_in[5];

    char* ws = (char*)d_ws;
    const size_t MB = 1ull << 20;
    u16* xb  = (u16*)(ws + 0);          // 4 MB  x as bf16 [4096][512]
    u16* Wqt = (u16*)(ws + 4 * MB);     // 4 MB  Wq^T bf16 [4096][512]
    u16* Wkt = (u16*)(ws + 8 * MB);
    u16* Wvt = (u16*)(ws + 12 * MB);
    u16* Wut = (u16*)(ws + 16 * MB);    // 4 MB  Wu^T bf16 [512][4096]
    u16* Qb  = (u16*)(ws + 20 * MB);    // 32 MB [bh][t][d] (pre-scaled, incl. log2e)
    u16* Kb  = (u16*)(ws + 52 * MB);    // 32 MB [bh][t][d]
    u16* Vb  = (u16*)(ws + 84 * MB);    // 32 MB [bh][t][d]
    u16* Vtb = (u16*)(ws + 116 * MB);   // 32 MB [bh][d][t]
    u16* Ob  = (u16*)(ws + 84 * MB);    // 32 MB [b*t][h*d]  (aliases Vb: V dead after transpose)

    cvt_kernel<<<2048, 256, 0, stream>>>(x, xb, 2 * 2048 * 512);
    transpose_cvt<<<dim3(64, 8), 256, 0, stream>>>(Wq, Wqt, 512, 4096);
    transpose_cvt<<<dim3(64, 8), 256, 0, stream>>>(Wk, Wkt, 512, 4096);
    transpose_cvt<<<dim3(64, 8), 256, 0, stream>>>(Wv, Wvt, 512, 4096);
    transpose_cvt<<<dim3(8, 64), 256, 0, stream>>>(Wu, Wut, 4096, 512);

    // 512^-0.5 * log2(e): softmax runs in base-2 (exp2f), fold conversion into Q scale
    const float s2 = 0.06375871593f;
    gemm_bt<0><<<dim3(32, 32), 256, 0, stream>>>(xb, Wqt, s2,   nullptr, Qb, 512);
    gemm_bt<0><<<dim3(32, 32), 256, 0, stream>>>(xb, Wkt, 1.0f, nullptr, Kb, 512);
    gemm_bt<0><<<dim3(32, 32), 256, 0, stream>>>(xb, Wvt, 1.0f, nullptr, Vb, 512);

    transpose_bh<<<dim3(8, 32, 16), 256, 0, stream>>>(Vb, Vtb);

    attn_kernel<<<256, 512, 0, stream>>>(Qb, Kb, Vtb, Ob);

    gemm_bt<1><<<dim3(4, 32), 256, 0, stream>>>(Ob, Wut, 1.0f, bu, d_out, 4096);
}

// Round 7
// 497.814 us; speedup vs baseline: 1.1666x; 1.1666x over previous
//
#include <hip/hip_runtime.h>

typedef unsigned short u16;
typedef unsigned short ushort8 __attribute__((ext_vector_type(8)));
typedef unsigned short us4 __attribute__((ext_vector_type(4)));
typedef __bf16 bf16x8 __attribute__((ext_vector_type(8)));
typedef float f32x4 __attribute__((ext_vector_type(4)));

#define DEV static __device__ __forceinline__

// ---------- helpers ----------
DEV u16 f2bf(float f) {   // round-to-nearest-even f32 -> bf16
    unsigned int u = __builtin_bit_cast(unsigned int, f);
    u += 0x7FFFu + ((u >> 16) & 1u);
    return (u16)(u >> 16);
}

DEV f32x4 mfma16(ushort8 a, ushort8 b, f32x4 c) {
    return __builtin_amdgcn_mfma_f32_16x16x32_bf16((bf16x8)a, (bf16x8)b, c, 0, 0, 0);
}

DEV void gload_lds16(const void* g, void* l) {   // async global->LDS, dst = base + lane*16
    __builtin_amdgcn_global_load_lds(
        (const __attribute__((address_space(1))) void*)g,
        (__attribute__((address_space(3))) void*)l, 16, 0, 0);
}

// ---------- fp32 -> bf16 elementwise ----------
__global__ void cvt_kernel(const float* __restrict__ in, u16* __restrict__ out, int n) {
    int i = (blockIdx.x * 256 + threadIdx.x) * 4;
    if (i >= n) return;
    float4 f = *(const float4*)(in + i);
    us4 o;
    o.x = f2bf(f.x); o.y = f2bf(f.y); o.z = f2bf(f.z); o.w = f2bf(f.w);
    *(us4*)(out + i) = o;
}

// ---------- fp32 [R][C] -> bf16 [C][R] (tiled, coalesced both sides) ----------
__global__ void transpose_cvt(const float* __restrict__ in, u16* __restrict__ out, int R, int C) {
    __shared__ u16 tile[64][72];
    int c0 = blockIdx.x << 6, r0 = blockIdx.y << 6;
    int tx = threadIdx.x & 63, ty = threadIdx.x >> 6;
    for (int i = 0; i < 64; i += 4) {
        int r = i + ty;
        tile[r][tx] = f2bf(in[(size_t)(r0 + r) * C + c0 + tx]);
    }
    __syncthreads();
    for (int i = 0; i < 64; i += 4) {
        int r = i + ty;
        out[(size_t)(c0 + r) * R + r0 + tx] = tile[tx][r];
    }
}

// ---------- bf16 [bh][2048][512] -> bf16 [bh][512][2048] ----------
__global__ void transpose_bh(const u16* __restrict__ in, u16* __restrict__ out) {
    __shared__ u16 tile[64][72];
    int bh = blockIdx.z;
    int d0 = blockIdx.x << 6, t0 = blockIdx.y << 6;
    int tx = threadIdx.x & 63, ty = threadIdx.x >> 6;
    const u16* src = in + (size_t)bh * 2048 * 512;
    u16* dst = out + (size_t)bh * 512 * 2048;
    for (int i = 0; i < 64; i += 4) {
        int r = i + ty;
        tile[r][tx] = src[(size_t)(t0 + r) * 512 + d0 + tx];
    }
    __syncthreads();
    for (int i = 0; i < 64; i += 4) {
        int r = i + ty;
        dst[(size_t)(d0 + r) * 2048 + t0 + tx] = tile[tx][r];
    }
}

// ---------- GEMM: C[M][?] = A[M][Kc](bf16) @ Bt[N][Kc]^T(bf16) ----------
template <int MODE>
__launch_bounds__(256, 2)
__global__ void gemm_bt(const u16* __restrict__ A, const u16* __restrict__ Bt,
                        float scale, const float* __restrict__ bias,
                        void* __restrict__ out, int Kc) {
    __shared__ u16 Asub[128 * 32];
    __shared__ u16 Bsub[128 * 32];
    const int tid = threadIdx.x, lane = tid & 63, wv = tid >> 6;
    const int bm = blockIdx.y << 7, bn = blockIdx.x << 7;
    const int wr = (wv >> 1) << 6, wc = (wv & 1) << 6;
    const int lr = lane & 15, hi = lane >> 4;

    f32x4 acc[4][4] = {};

    int off0 = (wv * 2048 + lane * 16) >> 1;
    int row0 = off0 >> 5, k0e = off0 & 31;
    int off1 = off0 + 512;
    int row1 = off1 >> 5, k1e = off1 & 31;

    const u16* Ag0 = A + (size_t)(bm + row0) * Kc + k0e;
    const u16* Ag1 = A + (size_t)(bm + row1) * Kc + k1e;
    const u16* Bg0 = Bt + (size_t)(bn + row0) * Kc + k0e;
    const u16* Bg1 = Bt + (size_t)(bn + row1) * Kc + k1e;

    for (int kk = 0; kk < Kc; kk += 32) {
        __syncthreads();
        gload_lds16(Ag0 + kk, &Asub[wv * 1024]);
        gload_lds16(Ag1 + kk, &Asub[wv * 1024 + 512]);
        gload_lds16(Bg0 + kk, &Bsub[wv * 1024]);
        gload_lds16(Bg1 + kk, &Bsub[wv * 1024 + 512]);
        __syncthreads();

        ushort8 a[4], b[4];
#pragma unroll
        for (int m = 0; m < 4; ++m)
            a[m] = *(const ushort8*)&Asub[(wr + m * 16 + lr) * 32 + hi * 8];
#pragma unroll
        for (int n = 0; n < 4; ++n)
            b[n] = *(const ushort8*)&Bsub[(wc + n * 16 + lr) * 32 + hi * 8];
#pragma unroll
        for (int m = 0; m < 4; ++m)
#pragma unroll
            for (int n = 0; n < 4; ++n)
                acc[m][n] = mfma16(a[m], b[n], acc[m][n]);
    }

#pragma unroll
    for (int m = 0; m < 4; ++m)
#pragma unroll
        for (int n = 0; n < 4; ++n)
#pragma unroll
            for (int r = 0; r < 4; ++r) {
                int row = bm + wr + m * 16 + hi * 4 + r;
                int col = bn + wc + n * 16 + lr;
                float v = acc[m][n][r] * scale;
                if constexpr (MODE == 0) {
                    size_t dst = ((size_t)((row >> 11) * 8 + (col >> 9)) * 2048 + (row & 2047)) * 512
                                 + (col & 511);
                    ((u16*)out)[dst] = f2bf(v);
                } else {
                    ((float*)out)[(size_t)row * 512 + col] = v + bias[col];
                }
            }
}

// ---------- flash attention v7 ----------
// v7 = v5 memory schedule (K dbuf via global_load_lds, plain __syncthreads, inline
// post-barrier V loads) + T15 att[2] phase pipelining:
//   iter t issues S(t) MFMAs (no consumer until t+1), then runs softmax(t-1) on
//   s_prev in the MFMA shadow, writes P(t-1), barrier, PV(t-1).
//   Matrix pipe (S) and VALU (softmax) of consecutive tiles now overlap in-wave.
// S accumulators back to 2 chains (s_cur 8 + s_prev 8 regs = v5's 16; slack from
// the one-iteration consumption delay makes chain depth irrelevant).
__launch_bounds__(512, 2)
__global__ void attn_kernel(const u16* __restrict__ Q, const u16* __restrict__ K,
                            const u16* __restrict__ Vt, u16* __restrict__ O) {
    __shared__ u16 Klds[2][32 * 512];            // 2 x 32KB, XOR-swizzled rows
    __shared__ u16 Plds[2][128 * 40];            // [q][32 keys + 8 pad]
    __shared__ __align__(16) float red[2][128];  // per-row alpha
    __shared__ __align__(16) float lred[128];    // final l
    __shared__ int rflag[2][8];                  // per-wave "some row rescaled"

    const int tid = threadIdx.x, lane = tid & 63, wv = tid >> 6;
    const int lr = lane & 15, hi = lane >> 4;
    const int qh = wv >> 2, ds = wv & 3;         // PV decomposition

    // XCD-chunked bijective swizzle: 256 blocks = 8 XCDs x 32; 2 bh per XCD chunk
    const int flat = blockIdx.x;
    const int nid = (flat & 7) * 32 + (flat >> 3);
    const int bh = nid >> 4;
    const int q0 = (nid & 15) << 7;

    // Q fragments (B-operand: col=lane&15 -> q-row wv*16+lr, k-slice hi*8..+8)
    ushort8 qf[16];
    {
        const char* Qg = (const char*)(Q + ((size_t)bh * 2048 + q0 + wv * 16 + lr) * 512) + hi * 16;
#pragma unroll
        for (int ks = 0; ks < 16; ++ks) qf[ks] = *(const ushort8*)(Qg + ks * 64);
    }

    f32x4 acc[4][8] = {};   // [q 16-block within 64-row half][d 16-frag within 128-wide slice]
    float mrun = -1e30f, lrun = 0.f;   // per-lane, q = wv*16+lr (replicated over hi), base-2

    const char* Kg = (const char*)(K + (size_t)bh * 2048 * 512);
    const char* Vg = (const char*)(Vt + (size_t)bh * 512 * 2048);

    // S-phase: 32 MFMAs into two chains (keys lr / lr+16), zero-started
    auto s_phase = [&](const char* Kb, f32x4& s0, f32x4& s1) {
        s0 = (f32x4){0.f, 0.f, 0.f, 0.f};
        s1 = (f32x4){0.f, 0.f, 0.f, 0.f};
#pragma unroll
        for (int ks = 0; ks < 16; ++ks) {
            int swz = (ks * 64 + hi * 16) ^ ((lr & 7) << 4);
            ushort8 kf0 = *(const ushort8*)(Kb + lr * 1024 + swz);
            ushort8 kf1 = *(const ushort8*)(Kb + (lr + 16) * 1024 + swz);
            s0 = mfma16(kf0, qf[ks], s0);
            s1 = mfma16(kf1, qf[ks], s1);
        }
    };

    // softmax on a finished S pair; writes P/alpha/flag into slot pcb
    auto softmax_store = [&](const f32x4& s0, const f32x4& s1, int pcb) {
        float mx = fmaxf(fmaxf(fmaxf(s0[0], s0[1]), fmaxf(s0[2], s0[3])),
                         fmaxf(fmaxf(s1[0], s1[1]), fmaxf(s1[2], s1[3])));
        mx = fmaxf(mx, __shfl_xor(mx, 16));
        mx = fmaxf(mx, __shfl_xor(mx, 32));
        float a = 1.0f;
        bool upd = false;
        if (mx > mrun + 11.5f) { a = exp2f(mrun - mx); mrun = mx; upd = true; }   // defer-max
        float p[8];
#pragma unroll
        for (int r = 0; r < 4; ++r) {
            p[r]     = exp2f(s0[r] - mrun);
            p[4 + r] = exp2f(s1[r] - mrun);
        }
        float ps = ((p[0] + p[1]) + (p[2] + p[3])) + ((p[4] + p[5]) + (p[6] + p[7]));
        ps += __shfl_xor(ps, 16);
        ps += __shfl_xor(ps, 32);
        lrun = lrun * a + ps;

        const int qr = wv * 16 + lr;
        char* Pb = (char*)&Plds[pcb][0] + qr * 80;
        uint2 w01, w23;
        w01.x = (unsigned)f2bf(p[0]) | ((unsigned)f2bf(p[1]) << 16);
        w01.y = (unsigned)f2bf(p[2]) | ((unsigned)f2bf(p[3]) << 16);
        w23.x = (unsigned)f2bf(p[4]) | ((unsigned)f2bf(p[5]) << 16);
        w23.y = (unsigned)f2bf(p[6]) | ((unsigned)f2bf(p[7]) << 16);
        *(uint2*)(Pb + hi * 8) = w01;
        *(uint2*)(Pb + 32 + hi * 8) = w23;
        if (hi == 0) red[pcb][qr] = a;
        if (lane == 0) rflag[pcb][wv] = __any(upd) ? 1 : 0;
    };

    // rescale (defer-max gated) + PV for tile whose P sits in slot pcb, V tile at key ktv
    auto pv_phase = [&](int pcb, int ktv) {
        int anyupd = rflag[pcb][0] | rflag[pcb][1] | rflag[pcb][2] | rflag[pcb][3]
                   | rflag[pcb][4] | rflag[pcb][5] | rflag[pcb][6] | rflag[pcb][7];
        if (anyupd) {
#pragma unroll
            for (int mf = 0; mf < 4; ++mf) {
                f32x4 a4 = *(const f32x4*)&red[pcb][qh * 64 + mf * 16 + hi * 4];
#pragma unroll
                for (int nf = 0; nf < 8; ++nf)
#pragma unroll
                    for (int r = 0; r < 4; ++r) acc[mf][nf][r] *= a4[r];
            }
        }
        ushort8 pf[4];
#pragma unroll
        for (int mf = 0; mf < 4; ++mf)
            pf[mf] = *(const ushort8*)((const char*)&Plds[pcb][0]
                                       + (qh * 64 + mf * 16 + lr) * 80 + hi * 16);
        __builtin_amdgcn_s_setprio(1);
#pragma unroll
        for (int nf = 0; nf < 8; ++nf) {
            int d = ds * 128 + nf * 16 + lr;
            ushort8 vf = *(const ushort8*)(Vg + (size_t)d * 4096 + (size_t)ktv * 2 + hi * 16);
#pragma unroll
            for (int mf = 0; mf < 4; ++mf) acc[mf][nf] = mfma16(pf[mf], vf, acc[mf][nf]);
        }
        __builtin_amdgcn_s_setprio(0);
    };

    auto prefetch_k = [&](int tt) {   // stage K(tt) into buf tt&1
        const char* Kgt = Kg + (size_t)tt * 32 * 1024;
#pragma unroll
        for (int r4 = 0; r4 < 4; ++r4) {
            int r = wv * 4 + r4;
            gload_lds16(Kgt + (size_t)r * 1024 + ((lane ^ (r & 7)) << 4),
                        &Klds[tt & 1][(size_t)r * 512]);
        }
    };

    f32x4 s0c, s1c, s0p, s1p;

    // prologue: K(0) -> buf0
    prefetch_k(0);
    __syncthreads();                       // K0 ready

    // peeled iter 0: prefetch K(1), S(0); no softmax/PV yet
    prefetch_k(1);
    s_phase((const char*)&Klds[0][0], s0c, s1c);
    __syncthreads();                       // K1 DMA drained; S(0) reads of buf0 done

    for (int t = 1; t < 64; ++t) {
        if (t + 1 < 64) prefetch_k(t + 1);       // -> buf (t+1)&1 (= buf read by S(t-1), done)

        s0p = s0c; s1p = s1c;                     // retire S(t-1) results
        s_phase((const char*)&Klds[t & 1][0], s0c, s1c);   // S(t) in flight...
        softmax_store(s0p, s1p, (t - 1) & 1);     // ...while softmax(t-1) runs on VALU

        __syncthreads();   // P(t-1)/alpha visible; K(t+1) drained; buf[t&1] reads done

        pv_phase((t - 1) & 1, (t - 1) << 5);
    }

    // epilogue: tile 63
    softmax_store(s0c, s1c, 1);
    __syncthreads();
    pv_phase(1, 63 << 5);

    // final l for all 128 rows -> LDS
    if (hi == 0) lred[wv * 16 + lr] = lrun;
    __syncthreads();

    const int b = bh >> 3, h = bh & 7;
#pragma unroll
    for (int mf = 0; mf < 4; ++mf) {
        f32x4 lv = *(const f32x4*)&lred[qh * 64 + mf * 16 + hi * 4];
        f32x4 inv;
#pragma unroll
        for (int r = 0; r < 4; ++r) inv[r] = 1.0f / lv[r];
#pragma unroll
        for (int nf = 0; nf < 8; ++nf) {
            int d = ds * 128 + nf * 16 + lr;
#pragma unroll
            for (int r = 0; r < 4; ++r) {
                int t = q0 + qh * 64 + mf * 16 + hi * 4 + r;
                O[((size_t)(b * 2048 + t)) * 4096 + h * 512 + d] = f2bf(acc[mf][nf][r] * inv[r]);
            }
        }
    }
}

// ---------- host ----------
extern "C" void kernel_launch(void* const* d_in, const int* in_sizes, int n_in,
                              void* d_out, int out_size, void* d_ws, size_t ws_size,
                              hipStream_t stream) {
    const float* x  = (const float*)d_in[0];
    const float* Wq = (const float*)d_in[1];
    const float* Wk = (const float*)d_in[2];
    const float* Wv = (const float*)d_in[3];
    const float* Wu = (const float*)d_in[4];
    const float* bu = (const float*)d_in[5];

    char* ws = (char*)d_ws;
    const size_t MB = 1ull << 20;
    u16* xb  = (u16*)(ws + 0);          // 4 MB  x as bf16 [4096][512]
    u16* Wqt = (u16*)(ws + 4 * MB);     // 4 MB  Wq^T bf16 [4096][512]
    u16* Wkt = (u16*)(ws + 8 * MB);
    u16* Wvt = (u16*)(ws + 12 * MB);
    u16* Wut = (u16*)(ws + 16 * MB);    // 4 MB  Wu^T bf16 [512][4096]
    u16* Qb  = (u16*)(ws + 20 * MB);    // 32 MB [bh][t][d] (pre-scaled, incl. log2e)
    u16* Kb  = (u16*)(ws + 52 * MB);    // 32 MB [bh][t][d]
    u16* Vb  = (u16*)(ws + 84 * MB);    // 32 MB [bh][t][d]
    u16* Vtb = (u16*)(ws + 116 * MB);   // 32 MB [bh][d][t]
    u16* Ob  = (u16*)(ws + 84 * MB);    // 32 MB [b*t][h*d]  (aliases Vb: V dead after transpose)

    cvt_kernel<<<2048, 256, 0, stream>>>(x, xb, 2 * 2048 * 512);
    transpose_cvt<<<dim3(64, 8), 256, 0, stream>>>(Wq, Wqt, 512, 4096);
    transpose_cvt<<<dim3(64, 8), 256, 0, stream>>>(Wk, Wkt, 512, 4096);
    transpose_cvt<<<dim3(64, 8), 256, 0, stream>>>(Wv, Wvt, 512, 4096);
    transpose_cvt<<<dim3(8, 64), 256, 0, stream>>>(Wu, Wut, 4096, 512);

    // 512^-0.5 * log2(e): softmax runs in base-2 (exp2f), fold conversion into Q scale
    const float s2 = 0.06375871593f;
    gemm_bt<0><<<dim3(32, 32), 256, 0, stream>>>(xb, Wqt, s2,   nullptr, Qb, 512);
    gemm_bt<0><<<dim3(32, 32), 256, 0, stream>>>(xb, Wkt, 1.0f, nullptr, Kb, 512);
    gemm_bt<0><<<dim3(32, 32), 256, 0, stream>>>(xb, Wvt, 1.0f, nullptr, Vb, 512);

    transpose_bh<<<dim3(8, 32, 16), 256, 0, stream>>>(Vb, Vtb);

    attn_kernel<<<256, 512, 0, stream>>>(Qb, Kb, Vtb, Ob);

    gemm_bt<1><<<dim3(4, 32), 256, 0, stream>>>(Ob, Wut, 1.0f, bu, d_out, 4096);
}